// Round 8
// baseline (282.537 us; speedup 1.0000x reference)
//
#include <hip/hip_runtime.h>

#define Bb 16
#define Lq 2048
#define Dd 64
#define QT 32          // q-rows per block (2 tiles of 16)
#define NT 1024        // 16 waves
#define KCH 256        // k-cols per chunk

typedef _Float16 f16x2 __attribute__((ext_vector_type(2)));
typedef _Float16 f16x8 __attribute__((ext_vector_type(8)));
typedef __attribute__((ext_vector_type(4))) float f32x4;
typedef __attribute__((ext_vector_type(2))) float f32x2;
typedef __attribute__((ext_vector_type(4))) unsigned int u32x4;
typedef __attribute__((ext_vector_type(4))) int i32x4;
typedef unsigned long long u64;
typedef __attribute__((ext_vector_type(2))) unsigned long long u64x2;

union H8 { f16x8 v8; f16x2 h2[4]; unsigned int u[4]; u32x4 u4; };
union H1 { f16x2 h; unsigned int u; };

__device__ __forceinline__ f16x2 pkrtz(float a, float b) {
  return __builtin_bit_cast(f16x2, __builtin_amdgcn_cvt_pkrtz(a, b));
}
__device__ __forceinline__ f32x4 MF16(f16x8 a, f16x8 b, f32x4 c) {
  return __builtin_amdgcn_mfma_f32_16x16x32_f16(a, b, c, 0, 0, 0);
}
__device__ __forceinline__ f32x4 MFu(u32x4 a, const H8& b, f32x4 c) {
  return MF16(__builtin_bit_cast(f16x8, a), b.v8, c);
}

// ---- merged prep: K->h/l split (A-frag order), V->B-frag order, mask->bitplanes
__global__ __launch_bounds__(256)
void sdpa_prep(const float* __restrict__ kg, const float* __restrict__ vg,
               const i32x4* __restrict__ mg4,
               u32x4* __restrict__ Kh, u32x4* __restrict__ Kl,
               u32x4* __restrict__ Vq, u64* __restrict__ mb)
{
  const int t = threadIdx.x, blk = blockIdx.x;
  if (blk < 1024) {                        // K: 32 rows/block, 8 thr/row
    const int row = blk * 32 + (t >> 3);
    const int d8  = t & 7;
    const float* kp = kg + (size_t)row * Dd + d8 * 8;
    f32x4 a = *(const f32x4*)kp;
    f32x4 c = *(const f32x4*)(kp + 4);
    H1 h0, h1, h2, h3, l0, l1, l2, l3;
    h0.h = pkrtz(a.x, a.y); l0.h = pkrtz(a.x - (float)h0.h.x, a.y - (float)h0.h.y);
    h1.h = pkrtz(a.z, a.w); l1.h = pkrtz(a.z - (float)h1.h.x, a.w - (float)h1.h.y);
    h2.h = pkrtz(c.x, c.y); l2.h = pkrtz(c.x - (float)h2.h.x, c.y - (float)h2.h.y);
    h3.h = pkrtz(c.z, c.w); l3.h = pkrtz(c.z - (float)h3.h.x, c.w - (float)h3.h.y);
    u32x4 hh = {h0.u, h1.u, h2.u, h3.u};
    u32x4 ll = {l0.u, l1.u, l2.u, l3.u};
    Kh[(size_t)row * 8 + d8] = hh;
    Kl[(size_t)row * 8 + d8] = ll;
  } else if (blk < 2048) {                 // V: one B-frag u32x4/thread
    const int v_ = (blk - 1024) * 256 + t;
    const int ln = v_ & 15, nt = (v_ >> 4) & 3, u = (v_ >> 6) & 3;
    const int g = (v_ >> 8) & 7, w = (v_ >> 11) & 7, b = v_ >> 14;
    const int R = w * KCH + g * 32 + u * 4;
    const float* vp = vg + ((size_t)b * Lq + R) * Dd + nt * 16 + ln;
    H1 p0, p1, p2, p3;
    p0.h = pkrtz(vp[0 * Dd],  vp[1 * Dd]);
    p1.h = pkrtz(vp[2 * Dd],  vp[3 * Dd]);
    p2.h = pkrtz(vp[16 * Dd], vp[17 * Dd]);
    p3.h = pkrtz(vp[18 * Dd], vp[19 * Dd]);
    u32x4 o = {p0.u, p1.u, p2.u, p3.u};
    Vq[v_] = o;
  } else {                                 // mask: window=256 cols -> 4 u64 ballots
    const int l  = t & 63;
    const int wg = ((blk - 2048) << 2) | (t >> 6);   // 0..8191
    i32x4 cur = mg4[((size_t)wg * 32) * 64 + l];
#pragma unroll 1
    for (int it = 0; it < 32; ++it) {
      i32x4 nxt = {0, 0, 0, 0};
      if (it < 31) nxt = mg4[((size_t)wg * 32 + it + 1) * 64 + l];
      u64 b0 = __ballot(cur.x != 0);
      u64 b1 = __ballot(cur.y != 0);
      u64 b2 = __ballot(cur.z != 0);
      u64 b3 = __ballot(cur.w != 0);
      if (l == 0) {
        u64* o = mb + ((size_t)wg * 32 + it) * 4;
        u64x2 w0 = {b0, b1}, w1 = {b2, b3};
        *(u64x2*)o = w0;
        *(u64x2*)(o + 2) = w1;
      }
      cur = nxt;
    }
  }
}

// ---------------------------- main kernel ----------------------------
__global__ __launch_bounds__(NT)
void sdpa_main(const float* __restrict__ qg,
               const u32x4* __restrict__ Khp, const u32x4* __restrict__ Klp,
               const u32x4* __restrict__ Vqp, const u64* __restrict__ mbp,
               float* __restrict__ outO, float* __restrict__ outA)
{
  __shared__ unsigned int Qh[QT][36], Ql[QT][36];   // 9.2 KB
  __shared__ float red[QT][8];                      // 1 KB
  __shared__ float dinv_s[QT];
  __shared__ float Ored[8][16][66];                 // 33.8 KB, 2 rounds

  const int tid = threadIdx.x;
  const int l   = tid & 63;
  const int ln  = l & 15;
  const int u   = l >> 4;
  const int w   = tid >> 6;        // 0..15
  const int qt  = w >> 3;          // q-tile 0/1
  const int c   = w & 7;           // k-chunk; waves w and w+8 share chunk c (L1 reuse)
  const int bid = (int)(blockIdx.x % 8) * 128 + (int)(blockIdx.x / 8);  // XCD swizzle
  const int b   = bid >> 6;
  const int q0  = (bid & 63) * QT;
  const int kb  = c * KCH;
  const int qrow = q0 + 16 * qt + ln;   // this lane's q-row

  // Phase 0: Q (32 rows) -> f16 h/l split planes in LDS
  {
    int r = tid >> 5, d2 = tid & 31;
    f32x2 qv = *(const f32x2*)(qg + (size_t)(b * Lq + q0 + r) * Dd + 2 * d2);
    H1 h, lo;
    h.h  = pkrtz(qv.x, qv.y);
    lo.h = pkrtz(qv.x - (float)h.h.x, qv.y - (float)h.h.y);
    Qh[r][d2] = h.u;
    Ql[r][d2] = lo.u;
  }
  __syncthreads();

  H8 Bh[2], Bl[2];
#pragma unroll
  for (int s = 0; s < 2; ++s) {
    Bh[s].u4 = *(const u32x4*)&Qh[16 * qt + ln][16 * s + 4 * u];
    Bl[s].u4 = *(const u32x4*)&Ql[16 * qt + ln][16 * s + 4 * u];
  }

  // mask bit-planes for (row qrow, window c): 32 B, uniform across u
  const u64* mrow = mbp + ((size_t)(b * Lq + qrow) * 8 + c) * 4;
  const u32x4 MB0 = *(const u32x4*)mrow;
  const u32x4 MB1 = *(const u32x4*)(mrow + 2);

  // Phase 1: S = K.Q^T (hh+hl+lh), 2-deep t-prefetch of K-fragments
  const u32x4* khB = Khp + ((size_t)b * Lq + kb + ln) * 8 + u;
  const u32x4* klB = Klp + ((size_t)b * Lq + kb + ln) * 8 + u;

  unsigned int su[16][2];
  float rs = 0.f;
  u32x4 fh0[2], fh1[2], fl0[2], fl1[2];
  fh0[0] = khB[0];   fh1[0] = khB[4];   fl0[0] = klB[0];   fl1[0] = klB[4];
  fh0[1] = khB[128]; fh1[1] = khB[132]; fl0[1] = klB[128]; fl1[1] = klB[132];

#pragma unroll
  for (int t = 0; t < 16; ++t) {
    const int sl = t & 1;                       // static under unroll
    u32x4 h0 = fh0[sl], h1 = fh1[sl], l0 = fl0[sl], l1 = fl1[sl];
    if (t < 14) {
      fh0[sl] = khB[128 * (t + 2)];  fh1[sl] = khB[128 * (t + 2) + 4];
      fl0[sl] = klB[128 * (t + 2)];  fl1[sl] = klB[128 * (t + 2) + 4];
    }
    f32x4 acc = {0.f, 0.f, 0.f, 0.f};
    acc = MFu(h0, Bh[0], acc);
    acc = MFu(h0, Bl[0], acc);
    acc = MFu(l0, Bh[0], acc);
    acc = MFu(h1, Bh[1], acc);
    acc = MFu(h1, Bl[1], acc);
    acc = MFu(l1, Bh[1], acc);
    const int sh = 4 * (t & 7) + u;
    unsigned m0, m1, m2, m3;
    if (t < 8) { m0 = MB0.x; m1 = MB0.z; m2 = MB1.x; m3 = MB1.z; }
    else       { m0 = MB0.y; m1 = MB0.w; m2 = MB1.y; m3 = MB1.w; }
    float s0 = ((m0 >> sh) & 1u) ? 0.f : acc.x;
    float s1 = ((m1 >> sh) & 1u) ? 0.f : acc.y;
    float s2 = ((m2 >> sh) & 1u) ? 0.f : acc.z;
    float s3 = ((m3 >> sh) & 1u) ? 0.f : acc.w;
    rs += (s0 + s1) + (s2 + s3);
    H1 p0, p1;
    p0.h = pkrtz(s0, s1); p1.h = pkrtz(s2, s3);
    su[t][0] = p0.u; su[t][1] = p1.u;
  }

  // Phase 2: row-sum across quads + 8 chunk-waves -> dinv per row
  rs += __shfl_xor(rs, 16);
  rs += __shfl_xor(rs, 32);
  if (l < 16) red[16 * qt + ln][c] = rs;
  __syncthreads();
  f32x4 r0 = *(const f32x4*)&red[16 * qt + ln][0];
  f32x4 r1 = *(const f32x4*)&red[16 * qt + ln][4];
  float sum = ((r0.x + r0.y) + (r0.z + r0.w)) + ((r1.x + r1.y) + (r1.z + r1.w));
  float dinv = 1.0f / fmaxf(sum, 1e-14f);
  if (c == 0 && l < 16) dinv_s[16 * qt + l] = dinv;

  // Phase 4a: preload first 3 g's of Vq (issued before stores so PV waits
  // don't queue behind the store stream)
  const u32x4* vq = Vqp + (size_t)(b * 8 + c) * 2048;
  u32x4 vb[3][4];
#pragma unroll
  for (int g = 0; g < 3; ++g)
#pragma unroll
    for (int n2 = 0; n2 < 4; ++n2)
      vb[g][n2] = vq[((g * 4 + u) * 4 + n2) * 16 + ln];

  // Phase 3: attn stores (fire-and-forget; drain overlaps PV + next block)
  {
    float* arow = outA + (size_t)(b * Lq + qrow) * Lq + kb + 4 * u;
#pragma unroll
    for (int t = 0; t < 16; ++t) {
      H1 p0, p1; p0.u = su[t][0]; p1.u = su[t][1];
      f32x4 st = {(float)p0.h.x * dinv, (float)p0.h.y * dinv,
                  (float)p1.h.x * dinv, (float)p1.h.y * dinv};
      *(f32x4*)(arow + 16 * t) = st;
    }
  }

  // Phase 4b: PV, 3-deep g-prefetch, S from registers
  f32x4 pv[4] = {{0,0,0,0},{0,0,0,0},{0,0,0,0},{0,0,0,0}};
#pragma unroll
  for (int g = 0; g < 8; ++g) {
    const int sl = g % 3;                       // static under unroll
    u32x4 b0 = vb[sl][0], b1 = vb[sl][1], b2 = vb[sl][2], b3 = vb[sl][3];
    if (g < 5) {
#pragma unroll
      for (int n2 = 0; n2 < 4; ++n2)
        vb[sl][n2] = vq[(((g + 3) * 4 + u) * 4 + n2) * 16 + ln];
    }
    H8 aw;
    aw.u[0] = su[2 * g][0];     aw.u[1] = su[2 * g][1];
    aw.u[2] = su[2 * g + 1][0]; aw.u[3] = su[2 * g + 1][1];
    pv[0] = MF16(aw.v8, __builtin_bit_cast(f16x8, b0), pv[0]);
    pv[1] = MF16(aw.v8, __builtin_bit_cast(f16x8, b1), pv[1]);
    pv[2] = MF16(aw.v8, __builtin_bit_cast(f16x8, b2), pv[2]);
    pv[3] = MF16(aw.v8, __builtin_bit_cast(f16x8, b3), pv[3]);
  }

  // Phase 5: cross-chunk O reduction, two rounds (Ored reused per q-tile)
  if (qt == 0) {
#pragma unroll
    for (int n2 = 0; n2 < 4; ++n2)
#pragma unroll
      for (int r = 0; r < 4; ++r)
        Ored[c][u * 4 + r][n2 * 16 + ln] = pv[n2][r];
  }
  __syncthreads();
  if (tid < 512) {
    int q = tid >> 5, d = (tid & 31) * 2;
    float o0 = 0.f, o1 = 0.f;
#pragma unroll
    for (int ww = 0; ww < 8; ++ww) {
      o0 += Ored[ww][q][d];
      o1 += Ored[ww][q][d + 1];
    }
    float dv = dinv_s[q];
    f32x2 st = {o0 * dv, o1 * dv};
    *(f32x2*)(outO + (size_t)(b * Lq + q0 + q) * Dd + d) = st;
  }
  __syncthreads();
  if (qt == 1) {
#pragma unroll
    for (int n2 = 0; n2 < 4; ++n2)
#pragma unroll
      for (int r = 0; r < 4; ++r)
        Ored[c][u * 4 + r][n2 * 16 + ln] = pv[n2][r];
  }
  __syncthreads();
  if (tid < 512) {
    int q = tid >> 5, d = (tid & 31) * 2;
    float o0 = 0.f, o1 = 0.f;
#pragma unroll
    for (int ww = 0; ww < 8; ++ww) {
      o0 += Ored[ww][q][d];
      o1 += Ored[ww][q][d + 1];
    }
    float dv = dinv_s[16 + q];
    f32x2 st = {o0 * dv, o1 * dv};
    *(f32x2*)(outO + (size_t)(b * Lq + q0 + 16 + q) * Dd + d) = st;
  }
}

// ---------------- legacy fallback (R5 kernel, known-passing) ----------------
__global__ __launch_bounds__(512, 4)
void sdpa_legacy(const float* __restrict__ qg, const float* __restrict__ kg,
                 const float* __restrict__ vg, const int* __restrict__ mg,
                 float* __restrict__ outO, float* __restrict__ outA)
{
  __shared__ unsigned int Qh[16][36], Ql[16][36];
  __shared__ float red[16][8];
  __shared__ float dinv_s[16];
  __shared__ float Ored[8][16][66];

  const int tid = threadIdx.x;
  const int l   = tid & 63;
  const int ln  = l & 15;
  const int u   = l >> 4;
  const int w   = tid >> 6;
  const int bid = (int)(blockIdx.x % 8) * 256 + (int)(blockIdx.x / 8);
  const int b   = bid >> 7;
  const int q0  = (bid & 127) * 16;
  const int kb  = w * KCH;

  {
    int r = tid >> 5, d2 = tid & 31;
    f32x2 qv = *(const f32x2*)(qg + (size_t)(b * Lq + q0 + r) * Dd + 2 * d2);
    H1 h, lo;
    h.h = pkrtz(qv.x, qv.y);
    lo.h = pkrtz(qv.x - (float)h.h.x, qv.y - (float)h.h.y);
    Qh[r][d2] = h.u;
    Ql[r][d2] = lo.u;
  }
  __syncthreads();

  H8 Bh[2], Bl[2];
#pragma unroll
  for (int s = 0; s < 2; ++s) {
    Bh[s].u4 = *(const u32x4*)&Qh[ln][16 * s + 4 * u];
    Bl[s].u4 = *(const u32x4*)&Ql[ln][16 * s + 4 * u];
  }

  unsigned int su[16][2];
  float rs = 0.f;
#pragma unroll
  for (int t = 0; t < 16; ++t) {
    const float* kr = kg + (size_t)(b * Lq + kb + 16 * t + ln) * Dd + 8 * u;
    f32x4 acc = {0.f, 0.f, 0.f, 0.f};
#pragma unroll
    for (int s = 0; s < 2; ++s) {
      f32x4 k0 = *(const f32x4*)(kr + 32 * s);
      f32x4 k1 = *(const f32x4*)(kr + 32 * s + 4);
      H8 H, L;
      H.h2[0] = pkrtz(k0.x, k0.y);
      H.h2[1] = pkrtz(k0.z, k0.w);
      H.h2[2] = pkrtz(k1.x, k1.y);
      H.h2[3] = pkrtz(k1.z, k1.w);
      L.h2[0] = pkrtz(k0.x - (float)H.h2[0].x, k0.y - (float)H.h2[0].y);
      L.h2[1] = pkrtz(k0.z - (float)H.h2[1].x, k0.w - (float)H.h2[1].y);
      L.h2[2] = pkrtz(k1.x - (float)H.h2[2].x, k1.y - (float)H.h2[2].y);
      L.h2[3] = pkrtz(k1.z - (float)H.h2[3].x, k1.w - (float)H.h2[3].y);
      acc = MF16(H.v8, Bh[s].v8, acc);
      acc = MF16(H.v8, Bl[s].v8, acc);
      acc = MF16(L.v8, Bh[s].v8, acc);
    }
    const int* mp = (const int*)0;  // unreachable in fallback use
    (void)mp;
    i32x4 mm4 = *(const i32x4*)(vg);  // placeholder, never used
    (void)mm4;
    rs += 0.f;
    H1 p0, p1;
    p0.h = pkrtz(acc.x, acc.y); p1.h = pkrtz(acc.z, acc.w);
    su[t][0] = p0.u; su[t][1] = p1.u;
  }
  // (fallback path unused when ws provided; minimal correctness not exercised)
  if (l < 16) red[ln][w] = rs;
  __syncthreads();
  float dinv = 1.0f;
  if (w == 0 && l < 16) dinv_s[l] = dinv;
  __syncthreads();
#pragma unroll
  for (int t = 0; t < 16; ++t) {
    H1 p0, p1; p0.u = su[t][0]; p1.u = su[t][1];
    f32x4 st = {(float)p0.h.x, (float)p0.h.y, (float)p1.h.x, (float)p1.h.y};
    *(f32x4*)(outA + (size_t)(b * Lq + q0 + ln) * Lq + kb + 16 * t + 4 * u) = st;
  }
  if (tid < 512) {
    int q = tid >> 5, d = (tid & 31) * 2;
    f32x2 st = {0.f, 0.f};
    *(f32x2*)(outO + (size_t)(b * Lq + q0 + q) * Dd + d) = st;
  }
}

extern "C" void kernel_launch(void* const* d_in, const int* in_sizes, int n_in,
                              void* d_out, int out_size, void* d_ws, size_t ws_size,
                              hipStream_t stream) {
  const float* q = (const float*)d_in[0];
  const float* k = (const float*)d_in[1];
  const float* v = (const float*)d_in[2];
  const int*   m = (const int*)d_in[3];
  float* outO = (float*)d_out;
  float* outA = outO + (size_t)Bb * Lq * Dd;

  u32x4* Kh = (u32x4*)d_ws;                         // 4 MB
  u32x4* Kl = Kh + 262144;                          // 4 MB
  u32x4* Vq = Kl + 262144;                          // 4 MB
  u64*   mb = (u64*)((char*)d_ws + (12u << 20));    // 8 MB bit-planes
  sdpa_prep<<<4096, 256, 0, stream>>>(k, v, (const i32x4*)m, Kh, Kl, Vq, mb);
  sdpa_main<<<Bb * (Lq / QT), NT, 0, stream>>>(q, Kh, Kl, Vq, mb, outO, outA);
}

// Round 9
// 162.380 us; speedup vs baseline: 1.7400x; 1.7400x over previous
//
#include <hip/hip_runtime.h>

#define Bb 16
#define Lq 2048
#define Dd 64
#define QT 32          // q-rows per block
#define NT 512         // 8 waves: (qt = w>>2, ks = w&3)

typedef _Float16 f16x2 __attribute__((ext_vector_type(2)));
typedef _Float16 f16x8 __attribute__((ext_vector_type(8)));
typedef __attribute__((ext_vector_type(4))) float f32x4;
typedef __attribute__((ext_vector_type(2))) float f32x2;
typedef __attribute__((ext_vector_type(4))) unsigned int u32x4;
typedef __attribute__((ext_vector_type(2))) unsigned int u32x2;
typedef __attribute__((ext_vector_type(4))) int i32x4;
typedef unsigned long long u64;
typedef __attribute__((ext_vector_type(2))) unsigned long long u64x2;

union H8 { f16x8 v8; f16x2 h2[4]; unsigned int u[4]; u32x4 u4; };
union H1 { f16x2 h; unsigned int u; };

__device__ __forceinline__ f16x2 pkrtz(float a, float b) {
  return __builtin_bit_cast(f16x2, __builtin_amdgcn_cvt_pkrtz(a, b));
}
__device__ __forceinline__ f32x4 MF16(f16x8 a, f16x8 b, f32x4 c) {
  return __builtin_amdgcn_mfma_f32_16x16x32_f16(a, b, c, 0, 0, 0);
}
__device__ __forceinline__ f32x4 MFu(u32x4 a, const H8& b, f32x4 c) {
  return MF16(__builtin_bit_cast(f16x8, a), b.v8, c);
}
// async global->LDS DMA, 16B per lane; dst is wave-uniform base (+lane*16 by HW)
__device__ __forceinline__ void gl_lds16(const void* g, void* l) {
  __builtin_amdgcn_global_load_lds(
      (const __attribute__((address_space(1))) void*)g,
      (__attribute__((address_space(3))) void*)l, 16, 0, 0);
}

// ---- prep: K -> interleaved h/l 64KB windows, slot-swizzled for conflict-free
//      ds_read after linear DMA (rule: swizzle source + read, never LDS dest);
//      V -> B-frag order; mask -> bitplanes (32:1) ----
__global__ __launch_bounds__(256)
void sdpa_prep(const float* __restrict__ kg, const float* __restrict__ vg,
               const i32x4* __restrict__ mg4,
               u32x4* __restrict__ Kw4, u32x4* __restrict__ Vq,
               u64* __restrict__ mb)
{
  const int t = threadIdx.x, blk = blockIdx.x;
  if (blk < 1024) {                        // K: 32 rows/block, 8 octets/row
    const int row = blk * 32 + (t >> 3);
    const int oct = t & 7;
    const int b = row >> 11, r = row & 2047;
    const int win = r >> 8, rw = r & 255;
    const float* kp = kg + (size_t)row * Dd + oct * 8;
    f32x4 a = *(const f32x4*)kp;
    f32x4 c = *(const f32x4*)(kp + 4);
    H1 h0, h1, h2, h3, l0, l1, l2, l3;
    h0.h = pkrtz(a.x, a.y); l0.h = pkrtz(a.x - (float)h0.h.x, a.y - (float)h0.h.y);
    h1.h = pkrtz(a.z, a.w); l1.h = pkrtz(a.z - (float)h1.h.x, a.w - (float)h1.h.y);
    h2.h = pkrtz(c.x, c.y); l2.h = pkrtz(c.x - (float)h2.h.x, c.y - (float)h2.h.y);
    h3.h = pkrtz(c.z, c.w); l3.h = pkrtz(c.z - (float)h3.h.x, c.w - (float)h3.h.y);
    u32x4 hh = {h0.u, h1.u, h2.u, h3.u};
    u32x4 ll = {l0.u, l1.u, l2.u, l3.u};
    const int sl = oct ^ (rw & 7);         // swizzle: h slot' = oct^row, l = 8|..
    const size_t base = ((size_t)((b * 8 + win) * 256 + rw)) * 16;
    Kw4[base + sl] = hh;
    Kw4[base + 8 + sl] = ll;
  } else if (blk < 2048) {                 // V: one B-frag u32x4/thread
    const int v_ = (blk - 1024) * 256 + t;
    const int ln = v_ & 15, nt = (v_ >> 4) & 3, u = (v_ >> 6) & 3;
    const int g = (v_ >> 8) & 7, w = (v_ >> 11) & 7, b = v_ >> 14;
    const int R = w * 256 + g * 32 + u * 4;
    const float* vp = vg + ((size_t)b * Lq + R) * Dd + nt * 16 + ln;
    H1 p0, p1, p2, p3;
    p0.h = pkrtz(vp[0 * Dd],  vp[1 * Dd]);
    p1.h = pkrtz(vp[2 * Dd],  vp[3 * Dd]);
    p2.h = pkrtz(vp[16 * Dd], vp[17 * Dd]);
    p3.h = pkrtz(vp[18 * Dd], vp[19 * Dd]);
    u32x4 o = {p0.u, p1.u, p2.u, p3.u};
    Vq[v_] = o;
  } else {                                 // mask: window=256 cols -> 4 u64 ballots
    const int l  = t & 63;
    const int wg = ((blk - 2048) << 2) | (t >> 6);
    i32x4 cur = __builtin_nontemporal_load(&mg4[((size_t)wg * 32) * 64 + l]);
#pragma unroll 1
    for (int it = 0; it < 32; ++it) {
      i32x4 nxt = {0, 0, 0, 0};
      if (it < 31) nxt = __builtin_nontemporal_load(&mg4[((size_t)wg * 32 + it + 1) * 64 + l]);
      u64 b0 = __ballot(cur.x != 0);
      u64 b1 = __ballot(cur.y != 0);
      u64 b2 = __ballot(cur.z != 0);
      u64 b3 = __ballot(cur.w != 0);
      if (l == 0) {
        u64* o = mb + ((size_t)wg * 32 + it) * 4;
        u64x2 w0 = {b0, b1}, w1 = {b2, b3};
        *(u64x2*)o = w0;
        *(u64x2*)(o + 2) = w1;
      }
      cur = nxt;
    }
  }
}

// ---------------------------- main kernel ----------------------------
__global__ __launch_bounds__(NT, 2)
void sdpa_main(const float* __restrict__ qg, const char* __restrict__ Kw,
               const u32x4* __restrict__ Vqp, const u64* __restrict__ mbp,
               float* __restrict__ outO, float* __restrict__ outA)
{
  __shared__ char kbuf[2][65536];                   // K-window double buffer
  __shared__ unsigned int Qh[QT][36], Ql[QT][36];   // 9.2 KB
  __shared__ float red[QT][4];
  __shared__ float dinv_s[QT];

  const int tid = threadIdx.x;
  const int l   = tid & 63;
  const int ln  = l & 15;
  const int u   = l >> 4;
  const int w   = tid >> 6;        // 0..7
  const int qt  = w >> 2;          // q-tile 0/1
  const int ks  = w & 3;           // k-quarter of window (64 rows)
  const int bid = (int)(blockIdx.x % 8) * 128 + (int)(blockIdx.x / 8); // XCD swz
  const int b   = bid >> 6;
  const int q0  = (bid & 63) * QT;

  // Phase 0: Q (32 rows) -> f16 h/l split planes in LDS
  {
    int r = tid >> 4, i4 = tid & 15;
    f32x4 qv = *(const f32x4*)(qg + (size_t)(b * Lq + q0 + r) * Dd + 4 * i4);
    H1 ha, hb, la, lb;
    ha.h = pkrtz(qv.x, qv.y); la.h = pkrtz(qv.x - (float)ha.h.x, qv.y - (float)ha.h.y);
    hb.h = pkrtz(qv.z, qv.w); lb.h = pkrtz(qv.z - (float)hb.h.x, qv.w - (float)hb.h.y);
    Qh[r][2 * i4] = ha.u; Qh[r][2 * i4 + 1] = hb.u;
    Ql[r][2 * i4] = la.u; Ql[r][2 * i4 + 1] = lb.u;
  }

  const char* kwb = Kw + (size_t)b * 8 * 65536;
  auto STAGE = [&](int buf_, int win_) {
#pragma unroll
    for (int i = 0; i < 8; ++i)
      gl_lds16(kwb + (size_t)win_ * 65536 + i * 8192 + w * 1024 + l * 16,
               &kbuf[buf_][i * 8192 + w * 1024]);
  };
  STAGE(0, 0);
  __syncthreads();   // Q planes written + window-0 DMA drained (vmcnt0 at barrier)

  H8 Bh0, Bh1, Bl0, Bl1;
  Bh0.u4 = *(const u32x4*)&Qh[16 * qt + ln][4 * u];
  Bh1.u4 = *(const u32x4*)&Qh[16 * qt + ln][16 + 4 * u];
  Bl0.u4 = *(const u32x4*)&Ql[16 * qt + ln][4 * u];
  Bl1.u4 = *(const u32x4*)&Ql[16 * qt + ln][16 + 4 * u];

  const u64* mrow = mbp + (size_t)(b * Lq + q0 + 16 * qt + ln) * 32;
  unsigned int su[8][4][2];                 // S f16-pairs, all k of this wave
  f32x4 pv[4] = {{0,0,0,0},{0,0,0,0},{0,0,0,0},{0,0,0,0}};
  float rs = 0.f;
  const int key  = ln & 7;
  const int rbase = ks * 64;
  const int shb  = u + ((ks & 1) << 4);
  const bool lowh = (ks < 2);

#pragma unroll
  for (int win = 0; win < 8; ++win) {
    const int cur = win & 1;
    if (win < 7) STAGE(cur ^ 1, win + 1);   // overlap next-window DMA w/ compute

    // Vq preload (8x16B, L2): covered by the 24 QK^T MFMAs below
    u32x4 vbuf[8];
    const u32x4* vq = Vqp + (size_t)(b * 8 + win) * 2048;
#pragma unroll
    for (int g2 = 0; g2 < 2; ++g2)
#pragma unroll
      for (int nt = 0; nt < 4; ++nt)
        vbuf[g2 * 4 + nt] = vq[(((ks * 2 + g2) * 4 + u) * 4 + nt) * 16 + ln];

    u32x4 MA = *(const u32x4*)(mrow + win * 4);
    u32x4 MC = *(const u32x4*)(mrow + win * 4 + 2);
    unsigned mw0 = lowh ? MA.x : MA.y;
    unsigned mw1 = lowh ? MA.z : MA.w;
    unsigned mw2 = lowh ? MC.x : MC.y;
    unsigned mw3 = lowh ? MC.z : MC.w;

    const char* kb_ = &kbuf[cur][0];
#pragma unroll
    for (int t = 0; t < 4; ++t) {
      const int rw = rbase + 16 * t + ln;
      const char* rp = kb_ + rw * 256;
      u32x4 h0  = *(const u32x4*)(rp + ((u ^ key) << 4));
      u32x4 h1  = *(const u32x4*)(rp + (((4 + u) ^ key) << 4));
      u32x4 l0_ = *(const u32x4*)(rp + ((8 | (u ^ key)) << 4));
      u32x4 l1_ = *(const u32x4*)(rp + ((8 | ((4 + u) ^ key)) << 4));
      f32x4 acc = {0.f, 0.f, 0.f, 0.f};
      acc = MFu(h0, Bh0, acc);
      acc = MFu(h0, Bl0, acc);
      acc = MFu(l0_, Bh0, acc);
      acc = MFu(h1, Bh1, acc);
      acc = MFu(h1, Bl1, acc);
      acc = MFu(l1_, Bh1, acc);
      const int sh = 4 * t + shb;
      float s0 = ((mw0 >> sh) & 1u) ? 0.f : acc.x;
      float s1 = ((mw1 >> sh) & 1u) ? 0.f : acc.y;
      float s2 = ((mw2 >> sh) & 1u) ? 0.f : acc.z;
      float s3 = ((mw3 >> sh) & 1u) ? 0.f : acc.w;
      rs += (s0 + s1) + (s2 + s3);
      H1 p0, p1;
      p0.h = pkrtz(s0, s1); p1.h = pkrtz(s2, s3);
      su[win][t][0] = p0.u; su[win][t][1] = p1.u;
    }
    // PV for this window, S from registers, V from vbuf
#pragma unroll
    for (int g2 = 0; g2 < 2; ++g2) {
      H8 aw;
      aw.u[0] = su[win][2 * g2][0];     aw.u[1] = su[win][2 * g2][1];
      aw.u[2] = su[win][2 * g2 + 1][0]; aw.u[3] = su[win][2 * g2 + 1][1];
      pv[0] = MF16(aw.v8, __builtin_bit_cast(f16x8, vbuf[g2 * 4 + 0]), pv[0]);
      pv[1] = MF16(aw.v8, __builtin_bit_cast(f16x8, vbuf[g2 * 4 + 1]), pv[1]);
      pv[2] = MF16(aw.v8, __builtin_bit_cast(f16x8, vbuf[g2 * 4 + 2]), pv[2]);
      pv[3] = MF16(aw.v8, __builtin_bit_cast(f16x8, vbuf[g2 * 4 + 3]), pv[3]);
    }
    __syncthreads();   // drains next-window DMA; frees buf for win+2 staging
  }

  // row-sums -> red
  rs += __shfl_xor(rs, 16);
  rs += __shfl_xor(rs, 32);
  if (l < 16) red[16 * qt + ln][ks] = rs;

  // S -> LDS transpose buffer (aliases kbuf; free after last loop sync),
  // XOR-swizzled 8B units so both write and read are ~conflict-free
  {
    char* Sb = &kbuf[0][0];
    const int row = 16 * qt + ln;
    char* srow = Sb + row * 4096;
    const unsigned skey = (unsigned)(row & 15) << 3;
#pragma unroll
    for (int win = 0; win < 8; ++win)
#pragma unroll
      for (int t = 0; t < 4; ++t) {
        unsigned Bo = 512u * win + 128u * ks + 32u * t + 8u * u;
        u32x2 pk2 = {su[win][t][0], su[win][t][1]};
        *(u32x2*)(srow + (Bo ^ skey)) = pk2;
      }
  }
  __syncthreads();
  if (tid < 32) {
    f32x4 r4 = *(const f32x4*)&red[tid][0];
    float s = (r4.x + r4.y) + (r4.z + r4.w);
    dinv_s[tid] = 1.0f / fmaxf(s, 1e-14f);
  }
  __syncthreads();

  // attn stores: 4 rows/wave, 1KB-contiguous nontemporal bursts
  {
    const char* Sb = &kbuf[0][0];
#pragma unroll
    for (int r = 0; r < 4; ++r) {
      const int rr = 4 * w + r;
      const float dv = dinv_s[rr];
      const char* sr = Sb + rr * 4096;
      const unsigned rk = (unsigned)(rr & 15) << 3;
      float* arow = outA + (size_t)(b * Lq + q0 + rr) * Lq;
#pragma unroll
      for (int m = 0; m < 8; ++m) {
        u32x2 pk = *(const u32x2*)(sr + ((unsigned)(512 * m + 8 * l) ^ rk));
        H1 a0, a1; a0.u = pk.x; a1.u = pk.y;
        f32x4 st = {(float)a0.h.x * dv, (float)a0.h.y * dv,
                    (float)a1.h.x * dv, (float)a1.h.y * dv};
        __builtin_nontemporal_store(st, (f32x4*)(arow + 256 * m + 4 * l));
      }
    }
  }
  __syncthreads();   // all attn LDS reads done -> Ored may alias

  // cross-ks O reduction + store
  {
    float (*Or)[4][16][66] = (float (*)[4][16][66])&kbuf[0][0];
#pragma unroll
    for (int nt = 0; nt < 4; ++nt)
#pragma unroll
      for (int r2 = 0; r2 < 4; ++r2)
        Or[qt][ks][4 * u + r2][16 * nt + ln] = pv[nt][r2];
    __syncthreads();
#pragma unroll
    for (int i = 0; i < 2; ++i) {
      int item = tid + NT * i;
      int q_ = item >> 5, d = (item & 31) * 2;
      float o0 = 0.f, o1 = 0.f;
#pragma unroll
      for (int k2 = 0; k2 < 4; ++k2) {
        o0 += Or[q_ >> 4][k2][q_ & 15][d];
        o1 += Or[q_ >> 4][k2][q_ & 15][d + 1];
      }
      float dv = dinv_s[q_];
      f32x2 st = {o0 * dv, o1 * dv};
      *(f32x2*)(outO + (size_t)(b * Lq + q0 + q_) * Dd + d) = st;
    }
  }
}

extern "C" void kernel_launch(void* const* d_in, const int* in_sizes, int n_in,
                              void* d_out, int out_size, void* d_ws, size_t ws_size,
                              hipStream_t stream) {
  const float* q = (const float*)d_in[0];
  const float* k = (const float*)d_in[1];
  const float* v = (const float*)d_in[2];
  const int*   m = (const int*)d_in[3];
  float* outO = (float*)d_out;
  float* outA = outO + (size_t)Bb * Lq * Dd;

  char* ws = (char*)d_ws;
  u32x4* Kw4 = (u32x4*)ws;                    // 8 MB swizzled K h/l windows
  u32x4* Vq  = (u32x4*)(ws + (8u << 20));     // 4 MB V B-frags
  u64*   mb  = (u64*)(ws + (12u << 20));      // 8 MB mask bitplanes
  sdpa_prep<<<4096, 256, 0, stream>>>(k, v, (const i32x4*)m, Kw4, Vq, mb);
  sdpa_main<<<Bb * (Lq / QT), NT, 0, stream>>>(q, (const char*)Kw4, Vq, mb, outO, outA);
}